// Round 17
// baseline (247.090 us; speedup 1.0000x reference)
//
#include <hip/hip_runtime.h>
#include <hip/hip_bf16.h>

// GraphConv: out = relu( scatter_add_{edges}( edge_val * (feat @ W)[edge_col] -> edge_row ) )
// Dtypes: feat/W/edge_val = float32, edge_row/col = int32, OUTPUT = float32.
//
// R23 post-mortem (230.3us, best): accum near its random-gather roofline (67 vs 37us floor);
// build side = 163us for ~80us of bytes. Key: binscatter does NOT depend on gemm, yet they
// serialize. R24 (resubmitted; R13-R16 were infra timeouts) — role-merged kernels (NO
// inter-role sync -> deadlock impossible):
//   K0 prep   = wconv(64 blk) + hist(196 blk)           [independent roles]
//   K1 scan   = unchanged
//   K2 fused  = binscatter(196 blk) + gemm(391 blk @1024thr, 16 waves x 16 rows)
//   K3 accum  = unchanged (R23 reg-held single-read form)
// binscatter's ~55us hides under gemm's ~60us.

#define N_NODES 100000
#define N_EDGES 1600000
#define D 128
#define WCONV_BLOCKS ((D * D + 255) / 256)          // 64
#define GEMM_BLOCKS_K2 ((N_NODES + 255) / 256)      // 391 (256 rows/block @ 1024 thr)
#define CHUNK_A 8192
#define NBLK_A ((N_EDGES + CHUNK_A - 1) / CHUNK_A)  // 196
#define BUCKETS ((N_NODES + 127) / 128)             // 782 (bucket = row>>7)
#define N_SCAN (BUCKETS * NBLK_A)                   // 153,272
#define SCAN_BLK ((N_SCAN + 1023) / 1024)           // 150
#define BCAP 4608                                    // max bucket size (mean 2046, sd ~45)

typedef __attribute__((ext_vector_type(8))) short short8;
typedef __attribute__((ext_vector_type(4))) float floatx4;
typedef int  iv2 __attribute__((ext_vector_type(2)));
typedef int  iv4 __attribute__((ext_vector_type(4)));
typedef float fv4 __attribute__((ext_vector_type(4)));

union U16B { uint4 u4; short8 s8; uint u[4]; ushort us[8]; };

__device__ __forceinline__ ushort f32_to_bf16(float f) {
    uint b = __float_as_uint(f);
    return (ushort)((b + 0x7FFFu + ((b >> 16) & 1u)) >> 16);   // RNE; inputs finite
}
__device__ __forceinline__ float bf16_to_f32(ushort u) {
    return __uint_as_float((uint)u << 16);
}

// ---------------- K0 prep: wconv role (blocks 0..63) + hist role (blocks 64..259) -----------
// wconv: WB[((k>>3)*128 + n)*8 + (k&7)] = bf16(W[k*128+n]); block 0 zeroes lookback st.
// hist: one 8192-edge chunk -> LDS hist -> TRANSPOSED histT[bucket*NBLK_A+chunk].
__global__ __launch_bounds__(256) void prep_kernel(const float* __restrict__ W,
                                                   ushort* __restrict__ WB,
                                                   uint* __restrict__ st,
                                                   const int* __restrict__ edge_row,
                                                   int* __restrict__ histT) {
    const int bid = blockIdx.x, tid = threadIdx.x;
    if (bid < WCONV_BLOCKS || histT == nullptr) {   // wconv role
        const int o = bid * 256 + tid;
        if (o < D * D) {
            const int K8 = o >> 10, rem = o & 1023, n = rem >> 3, j = rem & 7;
            WB[o] = f32_to_bf16(W[(K8 * 8 + j) * D + n]);
        }
        if (st && bid == 0 && tid < 256) st[tid] = 0u;
        return;
    }
    // hist role
    __shared__ int hist[BUCKETS];
    const int hbid = bid - WCONV_BLOCKS;
    for (int i = tid; i < BUCKETS; i += 256) hist[i] = 0;
    __syncthreads();
    const int base = hbid * CHUNK_A;
    #pragma unroll
    for (int k = 0; k < CHUNK_A / 256; k++) {
        const int e = base + k * 256 + tid;
        if (e < N_EDGES) atomicAdd(&hist[edge_row[e] >> 7], 1);   // LDS atomic
    }
    __syncthreads();
    for (int i = tid; i < BUCKETS; i += 256) histT[i * NBLK_A + hbid] = hist[i];
}

// ---------------- scan: 150-block decoupled-lookback exclusive scan over histT --------------
// Emits baseST TRANSPOSED (baseST[blk*BUCKETS+bucket]) so binscatter staging is coalesced.
__global__ __launch_bounds__(1024) void scan_kernel(const int* __restrict__ histT,
                                                    int* __restrict__ baseST,
                                                    int* __restrict__ bucketOff,
                                                    uint* __restrict__ st) {
    __shared__ int wsum[16];
    __shared__ int s_run, s_base;
    const int tid = threadIdx.x, b = blockIdx.x;
    const int gid = b * 1024 + tid;
    const int lane = tid & 63, wave = tid >> 6;

    const int v = (gid < N_SCAN) ? histT[gid] : 0;
    int x = v;                                 // inclusive wave scan
    #pragma unroll
    for (int d = 1; d < 64; d <<= 1) {
        int y = __shfl_up(x, d, 64);
        if (lane >= d) x += y;
    }
    if (lane == 63) wsum[wave] = x;
    __syncthreads();
    if (tid == 0) {
        int run = 0;
        #pragma unroll
        for (int w = 0; w < 16; w++) { int t = wsum[w]; wsum[w] = run; run += t; }
        s_run = run;
        __hip_atomic_store(&st[b], (1u << 30) | (uint)run,
                           __ATOMIC_RELEASE, __HIP_MEMORY_SCOPE_AGENT);
    }
    __syncthreads();
    if (wave == 0) {                           // 64-wide parallel lookback
        int P = 0;
        int base = b;
        bool done = (b == 0);
        while (!done) {
            const int j = base - 1 - lane;
            uint w;
            if (j >= 0) {
                do {
                    w = __hip_atomic_load(&st[j], __ATOMIC_ACQUIRE, __HIP_MEMORY_SCOPE_AGENT);
                } while ((w >> 30) == 0u);
            } else w = 2u << 30;
            const unsigned long long m2 = __ballot((w >> 30) == 2u);
            int contrib;
            if (m2) {
                const int fl = (int)__ffsll(m2) - 1;
                contrib = (lane <= fl) ? (int)(w & 0x3FFFFFFFu) : 0;
                done = true;
            } else {
                contrib = (int)(w & 0x3FFFFFFFu);
                base -= 64;
            }
            #pragma unroll
            for (int mm = 1; mm < 64; mm <<= 1) contrib += __shfl_xor(contrib, mm, 64);
            P += contrib;
        }
        if (lane == 0) {
            __hip_atomic_store(&st[b], (2u << 30) | (uint)(P + s_run),
                               __ATOMIC_RELEASE, __HIP_MEMORY_SCOPE_AGENT);
            s_base = P;
        }
    }
    __syncthreads();
    if (gid < N_SCAN) {
        const int excl = s_base + wsum[wave] + (x - v);
        const int bucket = gid / NBLK_A;
        const int blk = gid - bucket * NBLK_A;
        baseST[blk * BUCKETS + bucket] = excl;   // transposed (scattered write, L2-absorbed)
        if (blk == 0) bucketOff[bucket] = excl;
    }
    if (gid == 0) bucketOff[BUCKETS] = N_EDGES;
}

// ---------------- K2 fused: binscatter role (blocks 0..nScatter-1) + gemm role --------------
// Roles are INDEPENDENT (no flags, no waiting): binscatter needs scan output only; gemm
// needs WB only. binscatter's latency hides under gemm's MFMA waves via co-residency.
__global__ __launch_bounds__(1024) void fused_kernel(const float* __restrict__ feat,
                                                     const ushort* __restrict__ WB,
                                                     ushort* __restrict__ support,
                                                     const int* __restrict__ edge_row,
                                                     const int* __restrict__ edge_col,
                                                     const float* __restrict__ edge_val,
                                                     const int* __restrict__ baseST,
                                                     iv2* __restrict__ sorted,
                                                     int nScatter) {
    __shared__ int cur[BUCKETS];
    const int bid = blockIdx.x, tid = threadIdx.x;
    if (bid < nScatter) {                      // ---- binscatter role (R23 body, 1024 thr)
        const int blk = bid;
        for (int i = tid; i < BUCKETS; i += 1024) cur[i] = baseST[blk * BUCKETS + i];
        __syncthreads();
        const int base = blk * CHUNK_A;
        #pragma unroll
        for (int k = 0; k < CHUNK_A / 1024; k += 2) {   // 2 independent chains/iter
            const int e0 = base + k * 1024 + tid;
            const int e1 = e0 + 1024;
            const bool v0 = (e0 < N_EDGES), v1 = (e1 < N_EDGES);
            int r0 = 0, c0 = 0, r1 = 0, c1 = 0;
            float w0 = 0.f, w1 = 0.f;
            if (v0) { r0 = edge_row[e0]; c0 = edge_col[e0]; w0 = edge_val[e0]; }
            if (v1) { r1 = edge_row[e1]; c1 = edge_col[e1]; w1 = edge_val[e1]; }
            if (v0) {
                const int p = atomicAdd(&cur[r0 >> 7], 1);  // LDS atomic; block-private region
                iv2 pk; pk.x = ((r0 & 127) << 17) | c0; pk.y = __float_as_int(w0);
                sorted[p] = pk;
            }
            if (v1) {
                const int p = atomicAdd(&cur[r1 >> 7], 1);
                iv2 pk; pk.x = ((r1 & 127) << 17) | c1; pk.y = __float_as_int(w1);
                sorted[p] = pk;
            }
        }
        return;
    }
    // ---- gemm role: 16 waves x 16 rows = 256 rows/block
    const int gbid = bid - nScatter;
    const int wave = tid >> 6, lane = tid & 63;
    const int row0 = gbid * 256 + wave * 16;
    const int m = lane & 15, g = lane >> 4;
    if (row0 >= N_NODES) return;               // wave-uniform

    floatx4 acc[8];
    const floatx4 z = {0.f, 0.f, 0.f, 0.f};
    #pragma unroll
    for (int t = 0; t < 8; t++) acc[t] = z;

    const float* arow = feat + (size_t)(row0 + m) * D;
    const ushort* wb = WB + g * 1024 + m * 8;
    #pragma unroll
    for (int s = 0; s < 4; s++) {
        float4 a0 = *(const float4*)(arow + s * 32 + g * 8);
        float4 a1 = *(const float4*)(arow + s * 32 + g * 8 + 4);
        U16B a;
        a.us[0] = f32_to_bf16(a0.x); a.us[1] = f32_to_bf16(a0.y);
        a.us[2] = f32_to_bf16(a0.z); a.us[3] = f32_to_bf16(a0.w);
        a.us[4] = f32_to_bf16(a1.x); a.us[5] = f32_to_bf16(a1.y);
        a.us[6] = f32_to_bf16(a1.z); a.us[7] = f32_to_bf16(a1.w);
        #pragma unroll
        for (int t = 0; t < 8; t++) {
            U16B b; b.u4 = *(const uint4*)(wb + s * 4096 + t * 128);
            // swapped: D = W^T-frag x feat-frag -> transposed C layout
            acc[t] = __builtin_amdgcn_mfma_f32_16x16x32_bf16(b.s8, a.s8, acc[t], 0, 0, 0);
        }
    }
    // lane (g,m) reg r = support[row0+m][t*16+g*4+r]: 8B vector store per t
    ushort* srow = support + (size_t)(row0 + m) * D + g * 4;
    #pragma unroll
    for (int t = 0; t < 8; t++) {
        union { ushort us[4]; uint2 u2; } o;
        #pragma unroll
        for (int r = 0; r < 4; r++) o.us[r] = f32_to_bf16(acc[t][r]);
        *(uint2*)(srow + t * 16) = o.u2;
    }
}

// ---------------- bucket_accum: single-read reg-held sort + accumulate (R23 form) -----------
__global__ __launch_bounds__(1024) void bucket_accum_kernel(const int* __restrict__ bucketOff,
                                                            const iv2* __restrict__ sorted,
                                                            const ushort* __restrict__ support,
                                                            float* __restrict__ out) {
    __shared__ iv2 sldsE[BCAP];                // 36.8 KB
    __shared__ int cnt[128], rowStart[128], cur[128];
    __shared__ int wtot;
    const int tid = threadIdx.x, b = blockIdx.x;
    const int s = bucketOff[b];
    const int nE = bucketOff[b + 1] - s;       // <= BCAP = 4608 -> <=5 edges/thread

    if (tid < 128) cnt[tid] = 0;
    __syncthreads();

    // load-once into named registers + count
    iv2 h0, h1, h2, h3, h4;
    {
        int i = tid;
        if (i < nE) { h0 = sorted[s + i]; i += 1024; }
        if (i < nE) { h1 = sorted[s + i]; i += 1024; }
        if (i < nE) { h2 = sorted[s + i]; i += 1024; }
        if (i < nE) { h3 = sorted[s + i]; i += 1024; }
        if (i < nE) { h4 = sorted[s + i]; }
    }
    {
        int i = tid;
        if (i < nE) { atomicAdd(&cnt[h0.x >> 17], 1); i += 1024; }
        if (i < nE) { atomicAdd(&cnt[h1.x >> 17], 1); i += 1024; }
        if (i < nE) { atomicAdd(&cnt[h2.x >> 17], 1); i += 1024; }
        if (i < nE) { atomicAdd(&cnt[h3.x >> 17], 1); i += 1024; }
        if (i < nE) { atomicAdd(&cnt[h4.x >> 17], 1); }
    }
    __syncthreads();
    // exclusive scan of cnt[128] using threads 0..127 (2 waves)
    const int lane = tid & 63;
    const int myc = (tid < 128) ? cnt[tid] : 0;
    int x = myc;
    #pragma unroll
    for (int d = 1; d < 64; d <<= 1) {
        int y = __shfl_up(x, d, 64);
        if (lane >= d) x += y;
    }
    if (tid == 63) wtot = x;
    __syncthreads();
    if (tid < 128) {
        const int excl = x - myc + ((tid >= 64) ? wtot : 0);
        rowStart[tid] = excl;
        cur[tid] = excl;
    }
    __syncthreads();
    {   // place from registers at row-sorted LDS slots
        int i = tid;
        if (i < nE) { sldsE[atomicAdd(&cur[h0.x >> 17], 1)] = h0; i += 1024; }
        if (i < nE) { sldsE[atomicAdd(&cur[h1.x >> 17], 1)] = h1; i += 1024; }
        if (i < nE) { sldsE[atomicAdd(&cur[h2.x >> 17], 1)] = h2; i += 1024; }
        if (i < nE) { sldsE[atomicAdd(&cur[h3.x >> 17], 1)] = h3; i += 1024; }
        if (i < nE) { sldsE[atomicAdd(&cur[h4.x >> 17], 1)] = h4; }
    }
    __syncthreads();

    // accumulate. group g = tid>>4 (0..63) handles rows g*2, g*2+1; part = tid&15 -> 8 cols
    const int g = tid >> 4, part = tid & 15;
    #pragma unroll
    for (int t = 0; t < 2; t++) {
        const int rl = g * 2 + t;
        const int grow = (b << 7) + rl;
        if (grow >= N_NODES) break;
        const int rs = rowStart[rl], re = rs + cnt[rl];

        float acc0[8], acc1[8];
        #pragma unroll
        for (int i = 0; i < 8; i++) { acc0[i] = 0.f; acc1[i] = 0.f; }

        int k = rs;
        for (; k + 3 < re; k += 4) {           // 4 gathers in flight (VGPR-friendly)
            const iv2 e0 = sldsE[k], e1 = sldsE[k + 1];
            const iv2 e2 = sldsE[k + 2], e3 = sldsE[k + 3];
            U16B s0; s0.u4 = *(const uint4*)(support + (size_t)(e0.x & 0x1FFFF) * D + part * 8);
            U16B s1; s1.u4 = *(const uint4*)(support + (size_t)(e1.x & 0x1FFFF) * D + part * 8);
            U16B s2; s2.u4 = *(const uint4*)(support + (size_t)(e2.x & 0x1FFFF) * D + part * 8);
            U16B s3; s3.u4 = *(const uint4*)(support + (size_t)(e3.x & 0x1FFFF) * D + part * 8);
            const float v0 = __int_as_float(e0.y);
            const float v1 = __int_as_float(e1.y);
            const float v2 = __int_as_float(e2.y);
            const float v3 = __int_as_float(e3.y);
            #pragma unroll
            for (int i = 0; i < 8; i++) {
                acc0[i] += bf16_to_f32(s0.us[i]) * v0;
                acc1[i] += bf16_to_f32(s1.us[i]) * v1;
                acc0[i] += bf16_to_f32(s2.us[i]) * v2;
                acc1[i] += bf16_to_f32(s3.us[i]) * v3;
            }
        }
        for (; k < re; ++k) {
            const iv2 e0 = sldsE[k];
            U16B s0; s0.u4 = *(const uint4*)(support + (size_t)(e0.x & 0x1FFFF) * D + part * 8);
            const float v0 = __int_as_float(e0.y);
            #pragma unroll
            for (int i = 0; i < 8; i++) acc0[i] += bf16_to_f32(s0.us[i]) * v0;
        }

        fv4 lo, hi;
        lo.x = fmaxf(acc0[0] + acc1[0], 0.f); lo.y = fmaxf(acc0[1] + acc1[1], 0.f);
        lo.z = fmaxf(acc0[2] + acc1[2], 0.f); lo.w = fmaxf(acc0[3] + acc1[3], 0.f);
        hi.x = fmaxf(acc0[4] + acc1[4], 0.f); hi.y = fmaxf(acc0[5] + acc1[5], 0.f);
        hi.z = fmaxf(acc0[6] + acc1[6], 0.f); hi.w = fmaxf(acc0[7] + acc1[7], 0.f);
        float* dst = out + (size_t)grow * D + part * 8;
        __builtin_nontemporal_store(lo, (fv4*)dst);
        __builtin_nontemporal_store(hi, (fv4*)(dst + 4));
    }
}

// ================= Fallback path (R3 atomic spmm) if ws too small ===========================
__global__ __launch_bounds__(256) void zero_f4_kernel(float4* __restrict__ acc, int n4) {
    int i = blockIdx.x * 256 + threadIdx.x;
    if (i < n4) acc[i] = make_float4(0.f, 0.f, 0.f, 0.f);
}
__global__ __launch_bounds__(256) void spmm_kernel(const ushort* __restrict__ support,
                                                   const float* __restrict__ edge_val,
                                                   const int* __restrict__ edge_row,
                                                   const int* __restrict__ edge_col,
                                                   float* __restrict__ out) {
    const long gtid = (long)blockIdx.x * 256 + threadIdx.x;
    const int edge = (int)(gtid >> 4);
    const int part = (int)(gtid & 15);
    if (edge >= N_EDGES) return;
    const int col = edge_col[edge];
    const int row = edge_row[edge];
    const float v = edge_val[edge];
    U16B s; s.u4 = *(const uint4*)(support + (size_t)col * D + part * 8);
    float* dst = out + (size_t)row * D + part * 8;
    #pragma unroll
    for (int i = 0; i < 8; i++) unsafeAtomicAdd(dst + i, bf16_to_f32(s.us[i]) * v);
}
__global__ __launch_bounds__(256) void relu_kernel(float4* __restrict__ out, int n4) {
    int i = blockIdx.x * 256 + threadIdx.x;
    if (i >= n4) return;
    float4 a = out[i];
    a.x = fmaxf(a.x, 0.f); a.y = fmaxf(a.y, 0.f);
    a.z = fmaxf(a.z, 0.f); a.w = fmaxf(a.w, 0.f);
    out[i] = a;
}

extern "C" void kernel_launch(void* const* d_in, const int* in_sizes, int n_in,
                              void* d_out, int out_size, void* d_ws, size_t ws_size,
                              hipStream_t stream) {
    (void)in_sizes; (void)n_in; (void)out_size;
    const float* feat     = (const float*)d_in[0];
    const float* W        = (const float*)d_in[1];
    const float* edge_val = (const float*)d_in[2];
    const int*   edge_row = (const int*)d_in[3];
    const int*   edge_col = (const int*)d_in[4];
    float* out = (float*)d_out;

    // ws layout (~39.7 MB, all 16B-aligned slots) — unchanged from R21-R23 (known good)
    char* ws = (char*)d_ws;
    size_t o = 0;
    ushort* support  = (ushort*)(ws + o); o += (size_t)N_NODES * D * sizeof(ushort);        // 25.6 MB
    ushort* WB       = (ushort*)(ws + o); o += (size_t)D * D * sizeof(ushort);              // 32 KB
    int*    histT    = (int*)(ws + o);    o += ((size_t)N_SCAN * 4 + 15) & ~15ull;          // 613 KB
    int*    baseST   = (int*)(ws + o);    o += ((size_t)N_SCAN * 4 + 15) & ~15ull;          // 613 KB
    int*    bucketOff= (int*)(ws + o);    o += ((size_t)(BUCKETS + 1) * 4 + 15) & ~15ull;
    uint*   st       = (uint*)(ws + o);   o += 256 * 4;                                     // lookback
    iv2*    sorted   = (iv2*)(ws + o);    o += (size_t)N_EDGES * 8;                         // 12.8 MB
    const size_t needed = o;

    if (ws_size >= needed) {
        prep_kernel<<<WCONV_BLOCKS + NBLK_A, 256, 0, stream>>>(W, WB, st, edge_row, histT);
        scan_kernel<<<SCAN_BLK, 1024, 0, stream>>>(histT, baseST, bucketOff, st);
        fused_kernel<<<NBLK_A + GEMM_BLOCKS_K2, 1024, 0, stream>>>(
            feat, WB, support, edge_row, edge_col, edge_val, baseST, sorted, NBLK_A);
        bucket_accum_kernel<<<BUCKETS, 1024, 0, stream>>>(bucketOff, sorted, support, out);
    } else {
        // R3 fallback: atomic spmm into d_out
        const int n4 = N_NODES * D / 4;
        zero_f4_kernel<<<(n4 + 255) / 256, 256, 0, stream>>>((float4*)out, n4);
        prep_kernel<<<WCONV_BLOCKS, 256, 0, stream>>>(W, WB, nullptr, nullptr, nullptr);
        fused_kernel<<<GEMM_BLOCKS_K2, 1024, 0, stream>>>(
            feat, WB, support, nullptr, nullptr, nullptr, nullptr, nullptr, 0);
        spmm_kernel<<<(int)(((long)N_EDGES * 16 + 255) / 256), 256, 0, stream>>>(
            support, edge_val, edge_row, edge_col, out);
        relu_kernel<<<(n4 + 255) / 256, 256, 0, stream>>>((float4*)out, n4);
    }
}

// Round 18
// 236.536 us; speedup vs baseline: 1.0446x; 1.0446x over previous
//
#include <hip/hip_runtime.h>
#include <hip/hip_bf16.h>

// GraphConv: out = relu( scatter_add_{edges}( edge_val * (feat @ W)[edge_col] -> edge_row ) )
// Dtypes: feat/W/edge_val = float32, edge_row/col = int32, OUTPUT = float32.
//
// R24 post-mortem (247.1us): binscatter+gemm co-residency REGRESSED (+16.8) — two
// memory-bound roles share L2/HBM => "sum" not "max"; 1024-thr gemm also lost block-
// scheduling smoothness. REVERT to R23 structure (230.3us, best).
// R25 = R23 + 4-way bucket-split binscatter: block (chunk,q) owns bucket quarter q of
// chunk's edges -> 784 blocks (3.06/CU, was 0.77) with single-writer-per-region PRESERVED
// (each (bucket,chunk) cursor owned by exactly one block). edge_row read 4x (L2-amortized
// across co-resident siblings); col/val read once by the owning block.

#define N_NODES 100000
#define N_EDGES 1600000
#define D 128
#define GEMM_BLOCKS ((N_NODES + 63) / 64)           // 1563
#define CHUNK_A 8192
#define NBLK_A ((N_EDGES + CHUNK_A - 1) / CHUNK_A)  // 196
#define BUCKETS ((N_NODES + 127) / 128)             // 782 (bucket = row>>7)
#define N_SCAN (BUCKETS * NBLK_A)                   // 153,272
#define SCAN_BLK ((N_SCAN + 1023) / 1024)           // 150
#define BCAP 4608                                    // max bucket size (mean 2046, sd ~45)
#define BS_SPLIT 4
#define BK_PER_SPLIT ((BUCKETS + BS_SPLIT - 1) / BS_SPLIT)  // 196

typedef __attribute__((ext_vector_type(8))) short short8;
typedef __attribute__((ext_vector_type(4))) float floatx4;
typedef int  iv2 __attribute__((ext_vector_type(2)));
typedef int  iv4 __attribute__((ext_vector_type(4)));
typedef float fv4 __attribute__((ext_vector_type(4)));

union U16B { uint4 u4; short8 s8; uint u[4]; ushort us[8]; };

__device__ __forceinline__ ushort f32_to_bf16(float f) {
    uint b = __float_as_uint(f);
    return (ushort)((b + 0x7FFFu + ((b >> 16) & 1u)) >> 16);   // RNE; inputs finite
}
__device__ __forceinline__ float bf16_to_f32(ushort u) {
    return __uint_as_float((uint)u << 16);
}

// ---------------- wconv: W -> WB (bf16 MFMA-fragment order); zero lookback st --------------
__global__ __launch_bounds__(256) void wconv_kernel(const float* __restrict__ W,
                                                    ushort* __restrict__ WB,
                                                    uint* __restrict__ st) {
    const int o = blockIdx.x * 256 + threadIdx.x;
    if (o < D * D) {
        const int K8 = o >> 10, rem = o & 1023, n = rem >> 3, j = rem & 7;
        WB[o] = f32_to_bf16(W[(K8 * 8 + j) * D + n]);
    }
    if (st && blockIdx.x == 0 && threadIdx.x < 256) st[threadIdx.x] = 0u;
}

// ---------------- GEMM launch: blocks 0..195 hist-ONLY, rest gemm-only (R23 form) -----------
__global__ __launch_bounds__(256) void gemm_kernel(const float* __restrict__ feat,
                                                   const ushort* __restrict__ WB,
                                                   ushort* __restrict__ support,
                                                   const int* __restrict__ edge_row,
                                                   int* __restrict__ histT) {
    const int bid = blockIdx.x, tid = threadIdx.x;
    if (histT != nullptr && bid < NBLK_A) {    // block-uniform: hist-only block
        __shared__ int hist[BUCKETS];
        for (int i = tid; i < BUCKETS; i += 256) hist[i] = 0;
        __syncthreads();
        const int base = bid * CHUNK_A;
        #pragma unroll
        for (int k = 0; k < CHUNK_A / 256; k++) {
            const int e = base + k * 256 + tid;
            if (e < N_EDGES) atomicAdd(&hist[edge_row[e] >> 7], 1);   // LDS atomic
        }
        __syncthreads();
        for (int i = tid; i < BUCKETS; i += 256) histT[i * NBLK_A + bid] = hist[i];
        return;
    }
    const int gbid = (histT != nullptr) ? bid - NBLK_A : bid;

    const int wave = tid >> 6, lane = tid & 63;
    const int row0 = gbid * 64 + wave * 16;
    const int m = lane & 15, g = lane >> 4;
    if (row0 >= N_NODES) return;               // wave-uniform

    floatx4 acc[8];
    const floatx4 z = {0.f, 0.f, 0.f, 0.f};
    #pragma unroll
    for (int t = 0; t < 8; t++) acc[t] = z;

    const float* arow = feat + (size_t)(row0 + m) * D;
    const ushort* wb = WB + g * 1024 + m * 8;
    #pragma unroll
    for (int s = 0; s < 4; s++) {
        float4 a0 = *(const float4*)(arow + s * 32 + g * 8);
        float4 a1 = *(const float4*)(arow + s * 32 + g * 8 + 4);
        U16B a;
        a.us[0] = f32_to_bf16(a0.x); a.us[1] = f32_to_bf16(a0.y);
        a.us[2] = f32_to_bf16(a0.z); a.us[3] = f32_to_bf16(a0.w);
        a.us[4] = f32_to_bf16(a1.x); a.us[5] = f32_to_bf16(a1.y);
        a.us[6] = f32_to_bf16(a1.z); a.us[7] = f32_to_bf16(a1.w);
        #pragma unroll
        for (int t = 0; t < 8; t++) {
            U16B b; b.u4 = *(const uint4*)(wb + s * 4096 + t * 128);
            // swapped: D = W^T-frag x feat-frag -> transposed C layout
            acc[t] = __builtin_amdgcn_mfma_f32_16x16x32_bf16(b.s8, a.s8, acc[t], 0, 0, 0);
        }
    }
    // lane (g,m) reg r = support[row0+m][t*16+g*4+r]: 8B vector store per t
    ushort* srow = support + (size_t)(row0 + m) * D + g * 4;
    #pragma unroll
    for (int t = 0; t < 8; t++) {
        union { ushort us[4]; uint2 u2; } o;
        #pragma unroll
        for (int r = 0; r < 4; r++) o.us[r] = f32_to_bf16(acc[t][r]);
        *(uint2*)(srow + t * 16) = o.u2;
    }
}

// ---------------- scan: 150-block decoupled-lookback exclusive scan over histT --------------
// Emits baseST TRANSPOSED (baseST[blk*BUCKETS+bucket]) so binscatter staging is coalesced.
__global__ __launch_bounds__(1024) void scan_kernel(const int* __restrict__ histT,
                                                    int* __restrict__ baseST,
                                                    int* __restrict__ bucketOff,
                                                    uint* __restrict__ st) {
    __shared__ int wsum[16];
    __shared__ int s_run, s_base;
    const int tid = threadIdx.x, b = blockIdx.x;
    const int gid = b * 1024 + tid;
    const int lane = tid & 63, wave = tid >> 6;

    const int v = (gid < N_SCAN) ? histT[gid] : 0;
    int x = v;                                 // inclusive wave scan
    #pragma unroll
    for (int d = 1; d < 64; d <<= 1) {
        int y = __shfl_up(x, d, 64);
        if (lane >= d) x += y;
    }
    if (lane == 63) wsum[wave] = x;
    __syncthreads();
    if (tid == 0) {
        int run = 0;
        #pragma unroll
        for (int w = 0; w < 16; w++) { int t = wsum[w]; wsum[w] = run; run += t; }
        s_run = run;
        __hip_atomic_store(&st[b], (1u << 30) | (uint)run,
                           __ATOMIC_RELEASE, __HIP_MEMORY_SCOPE_AGENT);
    }
    __syncthreads();
    if (wave == 0) {                           // 64-wide parallel lookback
        int P = 0;
        int base = b;
        bool done = (b == 0);
        while (!done) {
            const int j = base - 1 - lane;
            uint w;
            if (j >= 0) {
                do {
                    w = __hip_atomic_load(&st[j], __ATOMIC_ACQUIRE, __HIP_MEMORY_SCOPE_AGENT);
                } while ((w >> 30) == 0u);
            } else w = 2u << 30;
            const unsigned long long m2 = __ballot((w >> 30) == 2u);
            int contrib;
            if (m2) {
                const int fl = (int)__ffsll(m2) - 1;
                contrib = (lane <= fl) ? (int)(w & 0x3FFFFFFFu) : 0;
                done = true;
            } else {
                contrib = (int)(w & 0x3FFFFFFFu);
                base -= 64;
            }
            #pragma unroll
            for (int mm = 1; mm < 64; mm <<= 1) contrib += __shfl_xor(contrib, mm, 64);
            P += contrib;
        }
        if (lane == 0) {
            __hip_atomic_store(&st[b], (2u << 30) | (uint)(P + s_run),
                               __ATOMIC_RELEASE, __HIP_MEMORY_SCOPE_AGENT);
            s_base = P;
        }
    }
    __syncthreads();
    if (gid < N_SCAN) {
        const int excl = s_base + wsum[wave] + (x - v);
        const int bucket = gid / NBLK_A;
        const int blk = gid - bucket * NBLK_A;
        baseST[blk * BUCKETS + bucket] = excl;   // transposed (scattered write, L2-absorbed)
        if (blk == 0) bucketOff[bucket] = excl;
    }
    if (gid == 0) bucketOff[BUCKETS] = N_EDGES;
}

// ---------------- binscatter: 784 blocks = (chunk x bucket-quarter), LDS cursors ------------
// Block (chunk,q) scatters only edges whose bucket is in [q*196,(q+1)*196). Each
// (bucket,chunk) region has exactly ONE writing block (R15/R19 single-writer rule).
// edge_row read 4x (co-resident siblings -> L2 hits); col/val read once by owner.
__global__ __launch_bounds__(1024) void binscatter_kernel(const int* __restrict__ edge_row,
                                                          const int* __restrict__ edge_col,
                                                          const float* __restrict__ edge_val,
                                                          const int* __restrict__ baseST,
                                                          iv2* __restrict__ sorted) {
    __shared__ int cur[BK_PER_SPLIT];
    const int tid = threadIdx.x, bid = blockIdx.x;
    const int blk = bid >> 2;                  // chunk index (0..195)
    const int split = bid & 3;
    const int lo = split * BK_PER_SPLIT;
    const int hi = (lo + BK_PER_SPLIT < BUCKETS) ? lo + BK_PER_SPLIT : BUCKETS;
    for (int i = lo + tid; i < hi; i += 1024) cur[i - lo] = baseST[blk * BUCKETS + i];
    __syncthreads();
    const int base = blk * CHUNK_A;
    #pragma unroll
    for (int k = 0; k < CHUNK_A / 1024; k += 2) {       // 2 independent chains/iter
        const int e0 = base + k * 1024 + tid;
        const int e1 = e0 + 1024;
        const bool v0 = (e0 < N_EDGES), v1 = (e1 < N_EDGES);
        int r0 = 0, r1 = 0;
        if (v0) r0 = edge_row[e0];
        if (v1) r1 = edge_row[e1];
        const int b0 = r0 >> 7, b1 = r1 >> 7;
        if (v0 && b0 >= lo && b0 < hi) {
            const int p = atomicAdd(&cur[b0 - lo], 1);  // LDS atomic; block-private region
            iv2 pk; pk.x = ((r0 & 127) << 17) | edge_col[e0];
            pk.y = __float_as_int(edge_val[e0]);
            sorted[p] = pk;
        }
        if (v1 && b1 >= lo && b1 < hi) {
            const int p = atomicAdd(&cur[b1 - lo], 1);
            iv2 pk; pk.x = ((r1 & 127) << 17) | edge_col[e1];
            pk.y = __float_as_int(edge_val[e1]);
            sorted[p] = pk;
        }
    }
}

// ---------------- bucket_accum: single-read reg-held sort + accumulate (R23 form) -----------
__global__ __launch_bounds__(1024) void bucket_accum_kernel(const int* __restrict__ bucketOff,
                                                            const iv2* __restrict__ sorted,
                                                            const ushort* __restrict__ support,
                                                            float* __restrict__ out) {
    __shared__ iv2 sldsE[BCAP];                // 36.8 KB
    __shared__ int cnt[128], rowStart[128], cur[128];
    __shared__ int wtot;
    const int tid = threadIdx.x, b = blockIdx.x;
    const int s = bucketOff[b];
    const int nE = bucketOff[b + 1] - s;       // <= BCAP = 4608 -> <=5 edges/thread

    if (tid < 128) cnt[tid] = 0;
    __syncthreads();

    // load-once into named registers + count
    iv2 h0, h1, h2, h3, h4;
    {
        int i = tid;
        if (i < nE) { h0 = sorted[s + i]; i += 1024; }
        if (i < nE) { h1 = sorted[s + i]; i += 1024; }
        if (i < nE) { h2 = sorted[s + i]; i += 1024; }
        if (i < nE) { h3 = sorted[s + i]; i += 1024; }
        if (i < nE) { h4 = sorted[s + i]; }
    }
    {
        int i = tid;
        if (i < nE) { atomicAdd(&cnt[h0.x >> 17], 1); i += 1024; }
        if (i < nE) { atomicAdd(&cnt[h1.x >> 17], 1); i += 1024; }
        if (i < nE) { atomicAdd(&cnt[h2.x >> 17], 1); i += 1024; }
        if (i < nE) { atomicAdd(&cnt[h3.x >> 17], 1); i += 1024; }
        if (i < nE) { atomicAdd(&cnt[h4.x >> 17], 1); }
    }
    __syncthreads();
    // exclusive scan of cnt[128] using threads 0..127 (2 waves)
    const int lane = tid & 63;
    const int myc = (tid < 128) ? cnt[tid] : 0;
    int x = myc;
    #pragma unroll
    for (int d = 1; d < 64; d <<= 1) {
        int y = __shfl_up(x, d, 64);
        if (lane >= d) x += y;
    }
    if (tid == 63) wtot = x;
    __syncthreads();
    if (tid < 128) {
        const int excl = x - myc + ((tid >= 64) ? wtot : 0);
        rowStart[tid] = excl;
        cur[tid] = excl;
    }
    __syncthreads();
    {   // place from registers at row-sorted LDS slots
        int i = tid;
        if (i < nE) { sldsE[atomicAdd(&cur[h0.x >> 17], 1)] = h0; i += 1024; }
        if (i < nE) { sldsE[atomicAdd(&cur[h1.x >> 17], 1)] = h1; i += 1024; }
        if (i < nE) { sldsE[atomicAdd(&cur[h2.x >> 17], 1)] = h2; i += 1024; }
        if (i < nE) { sldsE[atomicAdd(&cur[h3.x >> 17], 1)] = h3; i += 1024; }
        if (i < nE) { sldsE[atomicAdd(&cur[h4.x >> 17], 1)] = h4; }
    }
    __syncthreads();

    // accumulate. group g = tid>>4 (0..63) handles rows g*2, g*2+1; part = tid&15 -> 8 cols
    const int g = tid >> 4, part = tid & 15;
    #pragma unroll
    for (int t = 0; t < 2; t++) {
        const int rl = g * 2 + t;
        const int grow = (b << 7) + rl;
        if (grow >= N_NODES) break;
        const int rs = rowStart[rl], re = rs + cnt[rl];

        float acc0[8], acc1[8];
        #pragma unroll
        for (int i = 0; i < 8; i++) { acc0[i] = 0.f; acc1[i] = 0.f; }

        int k = rs;
        for (; k + 3 < re; k += 4) {           // 4 gathers in flight (VGPR-friendly)
            const iv2 e0 = sldsE[k], e1 = sldsE[k + 1];
            const iv2 e2 = sldsE[k + 2], e3 = sldsE[k + 3];
            U16B s0; s0.u4 = *(const uint4*)(support + (size_t)(e0.x & 0x1FFFF) * D + part * 8);
            U16B s1; s1.u4 = *(const uint4*)(support + (size_t)(e1.x & 0x1FFFF) * D + part * 8);
            U16B s2; s2.u4 = *(const uint4*)(support + (size_t)(e2.x & 0x1FFFF) * D + part * 8);
            U16B s3; s3.u4 = *(const uint4*)(support + (size_t)(e3.x & 0x1FFFF) * D + part * 8);
            const float v0 = __int_as_float(e0.y);
            const float v1 = __int_as_float(e1.y);
            const float v2 = __int_as_float(e2.y);
            const float v3 = __int_as_float(e3.y);
            #pragma unroll
            for (int i = 0; i < 8; i++) {
                acc0[i] += bf16_to_f32(s0.us[i]) * v0;
                acc1[i] += bf16_to_f32(s1.us[i]) * v1;
                acc0[i] += bf16_to_f32(s2.us[i]) * v2;
                acc1[i] += bf16_to_f32(s3.us[i]) * v3;
            }
        }
        for (; k < re; ++k) {
            const iv2 e0 = sldsE[k];
            U16B s0; s0.u4 = *(const uint4*)(support + (size_t)(e0.x & 0x1FFFF) * D + part * 8);
            const float v0 = __int_as_float(e0.y);
            #pragma unroll
            for (int i = 0; i < 8; i++) acc0[i] += bf16_to_f32(s0.us[i]) * v0;
        }

        fv4 lo, hi;
        lo.x = fmaxf(acc0[0] + acc1[0], 0.f); lo.y = fmaxf(acc0[1] + acc1[1], 0.f);
        lo.z = fmaxf(acc0[2] + acc1[2], 0.f); lo.w = fmaxf(acc0[3] + acc1[3], 0.f);
        hi.x = fmaxf(acc0[4] + acc1[4], 0.f); hi.y = fmaxf(acc0[5] + acc1[5], 0.f);
        hi.z = fmaxf(acc0[6] + acc1[6], 0.f); hi.w = fmaxf(acc0[7] + acc1[7], 0.f);
        float* dst = out + (size_t)grow * D + part * 8;
        __builtin_nontemporal_store(lo, (fv4*)dst);
        __builtin_nontemporal_store(hi, (fv4*)(dst + 4));
    }
}

// ================= Fallback path (R3 atomic spmm) if ws too small ===========================
__global__ __launch_bounds__(256) void zero_f4_kernel(float4* __restrict__ acc, int n4) {
    int i = blockIdx.x * 256 + threadIdx.x;
    if (i < n4) acc[i] = make_float4(0.f, 0.f, 0.f, 0.f);
}
__global__ __launch_bounds__(256) void spmm_kernel(const ushort* __restrict__ support,
                                                   const float* __restrict__ edge_val,
                                                   const int* __restrict__ edge_row,
                                                   const int* __restrict__ edge_col,
                                                   float* __restrict__ out) {
    const long gtid = (long)blockIdx.x * 256 + threadIdx.x;
    const int edge = (int)(gtid >> 4);
    const int part = (int)(gtid & 15);
    if (edge >= N_EDGES) return;
    const int col = edge_col[edge];
    const int row = edge_row[edge];
    const float v = edge_val[edge];
    U16B s; s.u4 = *(const uint4*)(support + (size_t)col * D + part * 8);
    float* dst = out + (size_t)row * D + part * 8;
    #pragma unroll
    for (int i = 0; i < 8; i++) unsafeAtomicAdd(dst + i, bf16_to_f32(s.us[i]) * v);
}
__global__ __launch_bounds__(256) void relu_kernel(float4* __restrict__ out, int n4) {
    int i = blockIdx.x * 256 + threadIdx.x;
    if (i >= n4) return;
    float4 a = out[i];
    a.x = fmaxf(a.x, 0.f); a.y = fmaxf(a.y, 0.f);
    a.z = fmaxf(a.z, 0.f); a.w = fmaxf(a.w, 0.f);
    out[i] = a;
}

extern "C" void kernel_launch(void* const* d_in, const int* in_sizes, int n_in,
                              void* d_out, int out_size, void* d_ws, size_t ws_size,
                              hipStream_t stream) {
    (void)in_sizes; (void)n_in; (void)out_size;
    const float* feat     = (const float*)d_in[0];
    const float* W        = (const float*)d_in[1];
    const float* edge_val = (const float*)d_in[2];
    const int*   edge_row = (const int*)d_in[3];
    const int*   edge_col = (const int*)d_in[4];
    float* out = (float*)d_out;

    // ws layout (~39.7 MB, all 16B-aligned slots) — unchanged from R21-R23 (known good)
    char* ws = (char*)d_ws;
    size_t o = 0;
    ushort* support  = (ushort*)(ws + o); o += (size_t)N_NODES * D * sizeof(ushort);        // 25.6 MB
    ushort* WB       = (ushort*)(ws + o); o += (size_t)D * D * sizeof(ushort);              // 32 KB
    int*    histT    = (int*)(ws + o);    o += ((size_t)N_SCAN * 4 + 15) & ~15ull;          // 613 KB
    int*    baseST   = (int*)(ws + o);    o += ((size_t)N_SCAN * 4 + 15) & ~15ull;          // 613 KB
    int*    bucketOff= (int*)(ws + o);    o += ((size_t)(BUCKETS + 1) * 4 + 15) & ~15ull;
    uint*   st       = (uint*)(ws + o);   o += 256 * 4;                                     // lookback
    iv2*    sorted   = (iv2*)(ws + o);    o += (size_t)N_EDGES * 8;                         // 12.8 MB
    const size_t needed = o;

    if (ws_size >= needed) {
        wconv_kernel<<<(D * D + 255) / 256, 256, 0, stream>>>(W, WB, st);
        gemm_kernel<<<NBLK_A + GEMM_BLOCKS, 256, 0, stream>>>(feat, WB, support, edge_row,
                                                              histT);
        scan_kernel<<<SCAN_BLK, 1024, 0, stream>>>(histT, baseST, bucketOff, st);
        binscatter_kernel<<<NBLK_A * BS_SPLIT, 1024, 0, stream>>>(edge_row, edge_col,
                                                                  edge_val, baseST, sorted);
        bucket_accum_kernel<<<BUCKETS, 1024, 0, stream>>>(bucketOff, sorted, support, out);
    } else {
        // R3 fallback: atomic spmm into d_out
        const int n4 = N_NODES * D / 4;
        zero_f4_kernel<<<(n4 + 255) / 256, 256, 0, stream>>>((float4*)out, n4);
        wconv_kernel<<<(D * D + 255) / 256, 256, 0, stream>>>(W, WB, nullptr);
        gemm_kernel<<<GEMM_BLOCKS, 256, 0, stream>>>(feat, WB, support, nullptr, nullptr);
        spmm_kernel<<<(int)(((long)N_EDGES * 16 + 255) / 256), 256, 0, stream>>>(
            support, edge_val, edge_row, edge_col, out);
        relu_kernel<<<(n4 + 255) / 256, 256, 0, stream>>>((float4*)out, n4);
    }
}

// Round 20
// 229.456 us; speedup vs baseline: 1.0769x; 1.0309x over previous
//
#include <hip/hip_runtime.h>
#include <hip/hip_bf16.h>

// GraphConv: out = relu( scatter_add_{edges}( edge_val * (feat @ W)[edge_col] -> edge_row ) )
// Dtypes: feat/W/edge_val = float32, edge_row/col = int32, OUTPUT = float32.
//
// R26 = EXACT RESTORE of R23 (230.3us, measured best; resubmitted after R19 infra timeout):
//   wconv -> gemm(196 hist-only blocks + 1563 gemm blocks) -> scan -> binscatter(196x1024,
//   LDS cursors, x2 unroll) -> bucket_accum(reg-held single-read sort, 1024 thr).
// accum plateaued at 67.5+-0.5 across 6 configs (~3.5TB/s on 237MB random-gather traffic)
// = empirical fabric ceiling. Build-side structural alternatives falsified: R24 fusion
// +16.8, R25 bucket-split +6.2, R15/R19 global-cursor scatter (7.6-7.9x write amp).
// Session: 273.9 -> 230.3 us.

#define N_NODES 100000
#define N_EDGES 1600000
#define D 128
#define GEMM_BLOCKS ((N_NODES + 63) / 64)           // 1563
#define CHUNK_A 8192
#define NBLK_A ((N_EDGES + CHUNK_A - 1) / CHUNK_A)  // 196
#define BUCKETS ((N_NODES + 127) / 128)             // 782 (bucket = row>>7)
#define N_SCAN (BUCKETS * NBLK_A)                   // 153,272
#define SCAN_BLK ((N_SCAN + 1023) / 1024)           // 150
#define BCAP 4608                                    // max bucket size (mean 2046, sd ~45)

typedef __attribute__((ext_vector_type(8))) short short8;
typedef __attribute__((ext_vector_type(4))) float floatx4;
typedef int  iv2 __attribute__((ext_vector_type(2)));
typedef int  iv4 __attribute__((ext_vector_type(4)));
typedef float fv4 __attribute__((ext_vector_type(4)));

union U16B { uint4 u4; short8 s8; uint u[4]; ushort us[8]; };

__device__ __forceinline__ ushort f32_to_bf16(float f) {
    uint b = __float_as_uint(f);
    return (ushort)((b + 0x7FFFu + ((b >> 16) & 1u)) >> 16);   // RNE; inputs finite
}
__device__ __forceinline__ float bf16_to_f32(ushort u) {
    return __uint_as_float((uint)u << 16);
}

// ---------------- wconv: W -> WB (bf16 MFMA-fragment order); zero lookback st --------------
// WB[((k>>3)*128 + n)*8 + (k&7)] = bf16(W[k*128+n]).
__global__ __launch_bounds__(256) void wconv_kernel(const float* __restrict__ W,
                                                    ushort* __restrict__ WB,
                                                    uint* __restrict__ st) {
    const int o = blockIdx.x * 256 + threadIdx.x;
    if (o < D * D) {
        const int K8 = o >> 10, rem = o & 1023, n = rem >> 3, j = rem & 7;
        WB[o] = f32_to_bf16(W[(K8 * 8 + j) * D + n]);
    }
    if (st && blockIdx.x == 0 && threadIdx.x < 256) st[threadIdx.x] = 0u;
}

// ---------------- GEMM launch: blocks 0..195 hist-ONLY, rest gemm-only ----------------------
// Hist blocks dispatch first -> finish early, fully overlapped with gemm blocks (no tail).
__global__ __launch_bounds__(256) void gemm_kernel(const float* __restrict__ feat,
                                                   const ushort* __restrict__ WB,
                                                   ushort* __restrict__ support,
                                                   const int* __restrict__ edge_row,
                                                   int* __restrict__ histT) {
    const int bid = blockIdx.x, tid = threadIdx.x;
    if (histT != nullptr && bid < NBLK_A) {    // block-uniform: hist-only block
        __shared__ int hist[BUCKETS];
        for (int i = tid; i < BUCKETS; i += 256) hist[i] = 0;
        __syncthreads();
        const int base = bid * CHUNK_A;
        #pragma unroll
        for (int k = 0; k < CHUNK_A / 256; k++) {
            const int e = base + k * 256 + tid;
            if (e < N_EDGES) atomicAdd(&hist[edge_row[e] >> 7], 1);   // LDS atomic
        }
        __syncthreads();
        for (int i = tid; i < BUCKETS; i += 256) histT[i * NBLK_A + bid] = hist[i];
        return;
    }
    const int gbid = (histT != nullptr) ? bid - NBLK_A : bid;

    const int wave = tid >> 6, lane = tid & 63;
    const int row0 = gbid * 64 + wave * 16;
    const int m = lane & 15, g = lane >> 4;
    if (row0 >= N_NODES) return;               // wave-uniform

    floatx4 acc[8];
    const floatx4 z = {0.f, 0.f, 0.f, 0.f};
    #pragma unroll
    for (int t = 0; t < 8; t++) acc[t] = z;

    const float* arow = feat + (size_t)(row0 + m) * D;
    const ushort* wb = WB + g * 1024 + m * 8;
    #pragma unroll
    for (int s = 0; s < 4; s++) {
        float4 a0 = *(const float4*)(arow + s * 32 + g * 8);
        float4 a1 = *(const float4*)(arow + s * 32 + g * 8 + 4);
        U16B a;
        a.us[0] = f32_to_bf16(a0.x); a.us[1] = f32_to_bf16(a0.y);
        a.us[2] = f32_to_bf16(a0.z); a.us[3] = f32_to_bf16(a0.w);
        a.us[4] = f32_to_bf16(a1.x); a.us[5] = f32_to_bf16(a1.y);
        a.us[6] = f32_to_bf16(a1.z); a.us[7] = f32_to_bf16(a1.w);
        #pragma unroll
        for (int t = 0; t < 8; t++) {
            U16B b; b.u4 = *(const uint4*)(wb + s * 4096 + t * 128);
            // swapped: D = W^T-frag x feat-frag -> transposed C layout
            acc[t] = __builtin_amdgcn_mfma_f32_16x16x32_bf16(b.s8, a.s8, acc[t], 0, 0, 0);
        }
    }
    // lane (g,m) reg r = support[row0+m][t*16+g*4+r]: 8B vector store per t
    ushort* srow = support + (size_t)(row0 + m) * D + g * 4;
    #pragma unroll
    for (int t = 0; t < 8; t++) {
        union { ushort us[4]; uint2 u2; } o;
        #pragma unroll
        for (int r = 0; r < 4; r++) o.us[r] = f32_to_bf16(acc[t][r]);
        *(uint2*)(srow + t * 16) = o.u2;
    }
}

// ---------------- scan: 150-block decoupled-lookback exclusive scan over histT --------------
// Emits baseST TRANSPOSED (baseST[blk*BUCKETS+bucket]) so binscatter staging is coalesced.
__global__ __launch_bounds__(1024) void scan_kernel(const int* __restrict__ histT,
                                                    int* __restrict__ baseST,
                                                    int* __restrict__ bucketOff,
                                                    uint* __restrict__ st) {
    __shared__ int wsum[16];
    __shared__ int s_run, s_base;
    const int tid = threadIdx.x, b = blockIdx.x;
    const int gid = b * 1024 + tid;
    const int lane = tid & 63, wave = tid >> 6;

    const int v = (gid < N_SCAN) ? histT[gid] : 0;
    int x = v;                                 // inclusive wave scan
    #pragma unroll
    for (int d = 1; d < 64; d <<= 1) {
        int y = __shfl_up(x, d, 64);
        if (lane >= d) x += y;
    }
    if (lane == 63) wsum[wave] = x;
    __syncthreads();
    if (tid == 0) {
        int run = 0;
        #pragma unroll
        for (int w = 0; w < 16; w++) { int t = wsum[w]; wsum[w] = run; run += t; }
        s_run = run;
        __hip_atomic_store(&st[b], (1u << 30) | (uint)run,
                           __ATOMIC_RELEASE, __HIP_MEMORY_SCOPE_AGENT);
    }
    __syncthreads();
    if (wave == 0) {                           // 64-wide parallel lookback
        int P = 0;
        int base = b;
        bool done = (b == 0);
        while (!done) {
            const int j = base - 1 - lane;
            uint w;
            if (j >= 0) {
                do {
                    w = __hip_atomic_load(&st[j], __ATOMIC_ACQUIRE, __HIP_MEMORY_SCOPE_AGENT);
                } while ((w >> 30) == 0u);
            } else w = 2u << 30;
            const unsigned long long m2 = __ballot((w >> 30) == 2u);
            int contrib;
            if (m2) {
                const int fl = (int)__ffsll(m2) - 1;
                contrib = (lane <= fl) ? (int)(w & 0x3FFFFFFFu) : 0;
                done = true;
            } else {
                contrib = (int)(w & 0x3FFFFFFFu);
                base -= 64;
            }
            #pragma unroll
            for (int mm = 1; mm < 64; mm <<= 1) contrib += __shfl_xor(contrib, mm, 64);
            P += contrib;
        }
        if (lane == 0) {
            __hip_atomic_store(&st[b], (2u << 30) | (uint)(P + s_run),
                               __ATOMIC_RELEASE, __HIP_MEMORY_SCOPE_AGENT);
            s_base = P;
        }
    }
    __syncthreads();
    if (gid < N_SCAN) {
        const int excl = s_base + wsum[wave] + (x - v);
        const int bucket = gid / NBLK_A;
        const int blk = gid - bucket * NBLK_A;
        baseST[blk * BUCKETS + bucket] = excl;   // transposed (scattered write, L2-absorbed)
        if (blk == 0) bucketOff[bucket] = excl;
    }
    if (gid == 0) bucketOff[BUCKETS] = N_EDGES;
}

// ---------------- binscatter: 196 blocks x 1024 thr, LDS cursors, x2-unrolled ---------------
// pack = (rowLocal<<17) | col.  One block owns each written region (R15/R19 lesson).
__global__ __launch_bounds__(1024) void binscatter_kernel(const int* __restrict__ edge_row,
                                                          const int* __restrict__ edge_col,
                                                          const float* __restrict__ edge_val,
                                                          const int* __restrict__ baseST,
                                                          iv2* __restrict__ sorted) {
    __shared__ int cur[BUCKETS];
    const int tid = threadIdx.x, blk = blockIdx.x;
    for (int i = tid; i < BUCKETS; i += 1024) cur[i] = baseST[blk * BUCKETS + i];  // coalesced
    __syncthreads();
    const int base = blk * CHUNK_A;
    #pragma unroll
    for (int k = 0; k < CHUNK_A / 1024; k += 2) {       // 2 independent chains/iter
        const int e0 = base + k * 1024 + tid;
        const int e1 = e0 + 1024;
        const bool v0 = (e0 < N_EDGES), v1 = (e1 < N_EDGES);
        int r0 = 0, c0 = 0, r1 = 0, c1 = 0;
        float w0 = 0.f, w1 = 0.f;
        if (v0) { r0 = edge_row[e0]; c0 = edge_col[e0]; w0 = edge_val[e0]; }
        if (v1) { r1 = edge_row[e1]; c1 = edge_col[e1]; w1 = edge_val[e1]; }
        if (v0) {
            const int p = atomicAdd(&cur[r0 >> 7], 1);  // LDS atomic; block-private region
            iv2 pk; pk.x = ((r0 & 127) << 17) | c0; pk.y = __float_as_int(w0);
            sorted[p] = pk;
        }
        if (v1) {
            const int p = atomicAdd(&cur[r1 >> 7], 1);
            iv2 pk; pk.x = ((r1 & 127) << 17) | c1; pk.y = __float_as_int(w1);
            sorted[p] = pk;
        }
    }
}

// ---------------- bucket_accum: single-read reg-held sort + accumulate ----------------------
// One block per bucket (128 rows), 1024 threads = 64 groups x 16 lanes; group g owns rows
// g*2, g*2+1. Each thread holds its <=5 edges in NAMED registers (rule: no runtime-indexed
// arrays); count + place from registers -> sorted read ONCE. LDS 38.4KB -> 2 blk/CU.
__global__ __launch_bounds__(1024) void bucket_accum_kernel(const int* __restrict__ bucketOff,
                                                            const iv2* __restrict__ sorted,
                                                            const ushort* __restrict__ support,
                                                            float* __restrict__ out) {
    __shared__ iv2 sldsE[BCAP];                // 36.8 KB
    __shared__ int cnt[128], rowStart[128], cur[128];
    __shared__ int wtot;
    const int tid = threadIdx.x, b = blockIdx.x;
    const int s = bucketOff[b];
    const int nE = bucketOff[b + 1] - s;       // <= BCAP = 4608 -> <=5 edges/thread

    if (tid < 128) cnt[tid] = 0;
    __syncthreads();

    // load-once into named registers + count
    iv2 h0, h1, h2, h3, h4;
    {
        int i = tid;
        if (i < nE) { h0 = sorted[s + i]; i += 1024; }
        if (i < nE) { h1 = sorted[s + i]; i += 1024; }
        if (i < nE) { h2 = sorted[s + i]; i += 1024; }
        if (i < nE) { h3 = sorted[s + i]; i += 1024; }
        if (i < nE) { h4 = sorted[s + i]; }
    }
    {
        int i = tid;
        if (i < nE) { atomicAdd(&cnt[h0.x >> 17], 1); i += 1024; }
        if (i < nE) { atomicAdd(&cnt[h1.x >> 17], 1); i += 1024; }
        if (i < nE) { atomicAdd(&cnt[h2.x >> 17], 1); i += 1024; }
        if (i < nE) { atomicAdd(&cnt[h3.x >> 17], 1); i += 1024; }
        if (i < nE) { atomicAdd(&cnt[h4.x >> 17], 1); }
    }
    __syncthreads();
    // exclusive scan of cnt[128] using threads 0..127 (2 waves)
    const int lane = tid & 63;
    const int myc = (tid < 128) ? cnt[tid] : 0;
    int x = myc;
    #pragma unroll
    for (int d = 1; d < 64; d <<= 1) {
        int y = __shfl_up(x, d, 64);
        if (lane >= d) x += y;
    }
    if (tid == 63) wtot = x;
    __syncthreads();
    if (tid < 128) {
        const int excl = x - myc + ((tid >= 64) ? wtot : 0);
        rowStart[tid] = excl;
        cur[tid] = excl;
    }
    __syncthreads();
    {   // place from registers at row-sorted LDS slots
        int i = tid;
        if (i < nE) { sldsE[atomicAdd(&cur[h0.x >> 17], 1)] = h0; i += 1024; }
        if (i < nE) { sldsE[atomicAdd(&cur[h1.x >> 17], 1)] = h1; i += 1024; }
        if (i < nE) { sldsE[atomicAdd(&cur[h2.x >> 17], 1)] = h2; i += 1024; }
        if (i < nE) { sldsE[atomicAdd(&cur[h3.x >> 17], 1)] = h3; i += 1024; }
        if (i < nE) { sldsE[atomicAdd(&cur[h4.x >> 17], 1)] = h4; }
    }
    __syncthreads();

    // accumulate. group g = tid>>4 (0..63) handles rows g*2, g*2+1; part = tid&15 -> 8 cols
    const int g = tid >> 4, part = tid & 15;
    #pragma unroll
    for (int t = 0; t < 2; t++) {
        const int rl = g * 2 + t;
        const int grow = (b << 7) + rl;
        if (grow >= N_NODES) break;
        const int rs = rowStart[rl], re = rs + cnt[rl];

        float acc0[8], acc1[8];
        #pragma unroll
        for (int i = 0; i < 8; i++) { acc0[i] = 0.f; acc1[i] = 0.f; }

        int k = rs;
        for (; k + 3 < re; k += 4) {           // 4 gathers in flight (VGPR-friendly)
            const iv2 e0 = sldsE[k], e1 = sldsE[k + 1];
            const iv2 e2 = sldsE[k + 2], e3 = sldsE[k + 3];
            U16B s0; s0.u4 = *(const uint4*)(support + (size_t)(e0.x & 0x1FFFF) * D + part * 8);
            U16B s1; s1.u4 = *(const uint4*)(support + (size_t)(e1.x & 0x1FFFF) * D + part * 8);
            U16B s2; s2.u4 = *(const uint4*)(support + (size_t)(e2.x & 0x1FFFF) * D + part * 8);
            U16B s3; s3.u4 = *(const uint4*)(support + (size_t)(e3.x & 0x1FFFF) * D + part * 8);
            const float v0 = __int_as_float(e0.y);
            const float v1 = __int_as_float(e1.y);
            const float v2 = __int_as_float(e2.y);
            const float v3 = __int_as_float(e3.y);
            #pragma unroll
            for (int i = 0; i < 8; i++) {
                acc0[i] += bf16_to_f32(s0.us[i]) * v0;
                acc1[i] += bf16_to_f32(s1.us[i]) * v1;
                acc0[i] += bf16_to_f32(s2.us[i]) * v2;
                acc1[i] += bf16_to_f32(s3.us[i]) * v3;
            }
        }
        for (; k < re; ++k) {
            const iv2 e0 = sldsE[k];
            U16B s0; s0.u4 = *(const uint4*)(support + (size_t)(e0.x & 0x1FFFF) * D + part * 8);
            const float v0 = __int_as_float(e0.y);
            #pragma unroll
            for (int i = 0; i < 8; i++) acc0[i] += bf16_to_f32(s0.us[i]) * v0;
        }

        fv4 lo, hi;
        lo.x = fmaxf(acc0[0] + acc1[0], 0.f); lo.y = fmaxf(acc0[1] + acc1[1], 0.f);
        lo.z = fmaxf(acc0[2] + acc1[2], 0.f); lo.w = fmaxf(acc0[3] + acc1[3], 0.f);
        hi.x = fmaxf(acc0[4] + acc1[4], 0.f); hi.y = fmaxf(acc0[5] + acc1[5], 0.f);
        hi.z = fmaxf(acc0[6] + acc1[6], 0.f); hi.w = fmaxf(acc0[7] + acc1[7], 0.f);
        float* dst = out + (size_t)grow * D + part * 8;
        __builtin_nontemporal_store(lo, (fv4*)dst);
        __builtin_nontemporal_store(hi, (fv4*)(dst + 4));
    }
}

// ================= Fallback path (R3 atomic spmm) if ws too small ===========================
__global__ __launch_bounds__(256) void zero_f4_kernel(float4* __restrict__ acc, int n4) {
    int i = blockIdx.x * 256 + threadIdx.x;
    if (i < n4) acc[i] = make_float4(0.f, 0.f, 0.f, 0.f);
}
__global__ __launch_bounds__(256) void spmm_kernel(const ushort* __restrict__ support,
                                                   const float* __restrict__ edge_val,
                                                   const int* __restrict__ edge_row,
                                                   const int* __restrict__ edge_col,
                                                   float* __restrict__ out) {
    const long gtid = (long)blockIdx.x * 256 + threadIdx.x;
    const int edge = (int)(gtid >> 4);
    const int part = (int)(gtid & 15);
    if (edge >= N_EDGES) return;
    const int col = edge_col[edge];
    const int row = edge_row[edge];
    const float v = edge_val[edge];
    U16B s; s.u4 = *(const uint4*)(support + (size_t)col * D + part * 8);
    float* dst = out + (size_t)row * D + part * 8;
    #pragma unroll
    for (int i = 0; i < 8; i++) unsafeAtomicAdd(dst + i, bf16_to_f32(s.us[i]) * v);
}
__global__ __launch_bounds__(256) void relu_kernel(float4* __restrict__ out, int n4) {
    int i = blockIdx.x * 256 + threadIdx.x;
    if (i >= n4) return;
    float4 a = out[i];
    a.x = fmaxf(a.x, 0.f); a.y = fmaxf(a.y, 0.f);
    a.z = fmaxf(a.z, 0.f); a.w = fmaxf(a.w, 0.f);
    out[i] = a;
}

extern "C" void kernel_launch(void* const* d_in, const int* in_sizes, int n_in,
                              void* d_out, int out_size, void* d_ws, size_t ws_size,
                              hipStream_t stream) {
    (void)in_sizes; (void)n_in; (void)out_size;
    const float* feat     = (const float*)d_in[0];
    const float* W        = (const float*)d_in[1];
    const float* edge_val = (const float*)d_in[2];
    const int*   edge_row = (const int*)d_in[3];
    const int*   edge_col = (const int*)d_in[4];
    float* out = (float*)d_out;

    // ws layout (~39.7 MB, all 16B-aligned slots)
    char* ws = (char*)d_ws;
    size_t o = 0;
    ushort* support  = (ushort*)(ws + o); o += (size_t)N_NODES * D * sizeof(ushort);        // 25.6 MB
    ushort* WB       = (ushort*)(ws + o); o += (size_t)D * D * sizeof(ushort);              // 32 KB
    int*    histT    = (int*)(ws + o);    o += ((size_t)N_SCAN * 4 + 15) & ~15ull;          // 613 KB
    int*    baseST   = (int*)(ws + o);    o += ((size_t)N_SCAN * 4 + 15) & ~15ull;          // 613 KB
    int*    bucketOff= (int*)(ws + o);    o += ((size_t)(BUCKETS + 1) * 4 + 15) & ~15ull;
    uint*   st       = (uint*)(ws + o);   o += 256 * 4;                                     // lookback
    iv2*    sorted   = (iv2*)(ws + o);    o += (size_t)N_EDGES * 8;                         // 12.8 MB
    const size_t needed = o;

    if (ws_size >= needed) {
        wconv_kernel<<<(D * D + 255) / 256, 256, 0, stream>>>(W, WB, st);
        gemm_kernel<<<NBLK_A + GEMM_BLOCKS, 256, 0, stream>>>(feat, WB, support, edge_row,
                                                              histT);
        scan_kernel<<<SCAN_BLK, 1024, 0, stream>>>(histT, baseST, bucketOff, st);
        binscatter_kernel<<<NBLK_A, 1024, 0, stream>>>(edge_row, edge_col, edge_val,
                                                       baseST, sorted);
        bucket_accum_kernel<<<BUCKETS, 1024, 0, stream>>>(bucketOff, sorted, support, out);
    } else {
        // R3 fallback: atomic spmm into d_out
        const int n4 = N_NODES * D / 4;
        zero_f4_kernel<<<(n4 + 255) / 256, 256, 0, stream>>>((float4*)out, n4);
        wconv_kernel<<<(D * D + 255) / 256, 256, 0, stream>>>(W, WB, nullptr);
        gemm_kernel<<<GEMM_BLOCKS, 256, 0, stream>>>(feat, WB, support, nullptr, nullptr);
        spmm_kernel<<<(int)(((long)N_EDGES * 16 + 255) / 256), 256, 0, stream>>>(
            support, edge_val, edge_row, edge_col, out);
        relu_kernel<<<(n4 + 255) / 256, 256, 0, stream>>>((float4*)out, n4);
    }
}